// Round 2
// baseline (226.432 us; speedup 1.0000x reference)
//
#include <hip/hip_runtime.h>
#include <hip/hip_bf16.h>

// ROIAlign (FPN multi-level, crop_and_resize style) for MI355X.
// Shapes (fixed by problem): B=2, N=512, C=256, OUT=7, IMG=1024,
// strides {4,8,16,32} -> fm H=W {256,128,64,32}.
// Reference output dtype is float16 -> harness reads d_out as FLOAT32
// ("else float*"), so we store f32.

#define B_SZ   2
#define N_ROI  512
#define CCH    256
#define OUT_S  7

__global__ __launch_bounds__(256)
void roialign_kernel(const float* __restrict__ fm2,
                     const float* __restrict__ fm3,
                     const float* __restrict__ fm4,
                     const float* __restrict__ fm5,
                     const float* __restrict__ rois,
                     float* __restrict__ out)
{
    const int bn = blockIdx.x;                 // 0 .. B*N-1
    const int b  = bn >> 9;                    // N=512
    const int t  = threadIdx.x;

    // ---- per-ROI scalar setup (uniform within block) ----
    const float4 roi = ((const float4*)rois)[bn];   // x1,y1,x2,y2
    const float x1 = roi.x, y1 = roi.y;
    const float w  = roi.z - roi.x;
    const float h  = roi.w - roi.y;

    float lvf = log2f(sqrtf(w * h) * (1.0f / 224.0f)) + 4.0f;
    int lv = (int)rintf(lvf);                  // round half-to-even, matches jnp.round
    lv = min(max(lv, 2), 5) - 2;               // 0..3

    const float* fms[4] = { fm2, fm3, fm4, fm5 };
    const int    hws[4] = { 256, 128, 64, 32 };
    const float  strd[4] = { 4.0f, 8.0f, 16.0f, 32.0f };

    const int    H      = hws[lv];             // H == W
    const float  stride = strd[lv];
    const float* fm     = fms[lv] + (size_t)b * (size_t)H * (size_t)H * CCH;

    // ---- sample coordinates into LDS (7 y's, 7 x's) ----
    __shared__ int   s_c0[2][OUT_S];   // [0]=y0, [1]=x0
    __shared__ int   s_c1[2][OUT_S];   // y1i / x1i
    __shared__ float s_fr[2][OUT_S];   // frac
    __shared__ int   s_vd[2][OUT_S];   // validity

    if (t < 2 * OUT_S) {
        const int axis = (t < OUT_S) ? 0 : 1;       // 0=y, 1=x
        const int j    = (axis == 0) ? t : t - OUT_S;
        const float lo  = (axis == 0) ? y1 : x1;
        const float ext = (axis == 0) ? h  : w;
        const float g = (float)j * (1.0f / 6.0f);
        // ref: ((lo + g*ext)/stride / H) * (H-1)
        const float coord = (lo + g * ext) * ((float)(H - 1) / (stride * (float)H));
        const int valid = (coord >= 0.0f) && (coord <= (float)(H - 1));
        float cl = fminf(fmaxf(coord, 0.0f), (float)(H - 1));
        int c0 = (int)floorf(cl);
        float fr = cl - (float)c0;
        int c1 = min(c0 + 1, H - 1);
        s_c0[axis][j] = c0;
        s_c1[axis][j] = c1;
        s_fr[axis][j] = fr;
        s_vd[axis][j] = valid;
    }
    __syncthreads();

    // ---- main: 49 cells, 4 at a time; 64 lanes * 4ch (float4) per cell ----
    const int sub  = t >> 6;          // 0..3 : cell offset within group of 4
    const int lane = t & 63;          // channel group
    const int c    = lane * 4;

    const size_t outBase = (size_t)bn * (OUT_S * OUT_S) * CCH;

    for (int cb = 0; cb < OUT_S * OUT_S; cb += 4) {
        const int cell = cb + sub;
        if (cell >= OUT_S * OUT_S) break;
        const int jy = cell / OUT_S;
        const int ix = cell - jy * OUT_S;

        const int   y0  = s_c0[0][jy];
        const int   y1i = s_c1[0][jy];
        const float yl  = s_fr[0][jy];
        const int   x0  = s_c0[1][ix];
        const int   x1i = s_c1[1][ix];
        const float xl  = s_fr[1][ix];
        const int   vld = s_vd[0][jy] & s_vd[1][ix];

        const float* rowT = fm + (size_t)y0  * H * CCH;
        const float* rowB = fm + (size_t)y1i * H * CCH;

        const float4 tl = *(const float4*)(rowT + x0  * CCH + c);
        const float4 tr = *(const float4*)(rowT + x1i * CCH + c);
        const float4 bl = *(const float4*)(rowB + x0  * CCH + c);
        const float4 br = *(const float4*)(rowB + x1i * CCH + c);

        float4 o;
        {
            const float tx = tl.x + (tr.x - tl.x) * xl;
            const float bx = bl.x + (br.x - bl.x) * xl;
            o.x = tx + (bx - tx) * yl;
        }
        {
            const float ty = tl.y + (tr.y - tl.y) * xl;
            const float by = bl.y + (br.y - bl.y) * xl;
            o.y = ty + (by - ty) * yl;
        }
        {
            const float tz = tl.z + (tr.z - tl.z) * xl;
            const float bz = bl.z + (br.z - bl.z) * xl;
            o.z = tz + (bz - tz) * yl;
        }
        {
            const float tw = tl.w + (tr.w - tl.w) * xl;
            const float bw = bl.w + (br.w - bl.w) * xl;
            o.w = tw + (bw - tw) * yl;
        }
        if (!vld) { o.x = 0.0f; o.y = 0.0f; o.z = 0.0f; o.w = 0.0f; }

        *(float4*)(out + outBase + (size_t)cell * CCH + c) = o;
    }
}

extern "C" void kernel_launch(void* const* d_in, const int* in_sizes, int n_in,
                              void* d_out, int out_size, void* d_ws, size_t ws_size,
                              hipStream_t stream) {
    const float* fm2  = (const float*)d_in[0];
    const float* fm3  = (const float*)d_in[1];
    const float* fm4  = (const float*)d_in[2];
    const float* fm5  = (const float*)d_in[3];
    const float* rois = (const float*)d_in[4];
    float* out = (float*)d_out;

    dim3 grid(B_SZ * N_ROI);
    dim3 block(256);
    hipLaunchKernelGGL(roialign_kernel, grid, block, 0, stream,
                       fm2, fm3, fm4, fm5, rois, out);
}

// Round 4
// 218.949 us; speedup vs baseline: 1.0342x; 1.0342x over previous
//
#include <hip/hip_runtime.h>

// ROIAlign (FPN multi-level, crop_and_resize style) for MI355X.
// Shapes (fixed): B=2, N=512, C=256, OUT=7, IMG=1024,
// strides {4,8,16,32} -> fm H=W {256,128,64,32}.
// Output read back by harness as float32 (reference dtype f16 -> "else float*").
//
// R3 structure: one 64-lane wave per (roi, cell). grid = 2*512*49/4 = 12544
// blocks x 256 threads. No LDS, no loop -> maximal memory-level parallelism
// (R2 was 1024 blocks with a serial 13-iter loop: latency-bound at ~3 TB/s
// effective while harness memsets prove 6.6 TB/s achievable).

#define B_SZ   2
#define N_ROI  512
#define CCH    256
#define OUT_S  7
#define NCELL  (OUT_S * OUT_S)

typedef float nfloat4 __attribute__((ext_vector_type(4)));  // native vec for nontemporal builtin

__global__ __launch_bounds__(256)
void roialign_kernel(const float* __restrict__ fm2,
                     const float* __restrict__ fm3,
                     const float* __restrict__ fm4,
                     const float* __restrict__ fm5,
                     const float* __restrict__ rois,
                     float* __restrict__ out)
{
    // global wave id -> (roi, cell). grid exactly covers 1024*49 waves.
    const int wid  = (blockIdx.x << 2) + (threadIdx.x >> 6);
    const int bn   = wid / NCELL;               // 0 .. B*N-1
    const int cell = wid - bn * NCELL;          // 0 .. 48
    const int b    = bn >> 9;                   // N=512
    const int jy   = cell / OUT_S;
    const int ix   = cell - jy * OUT_S;

    // ---- per-ROI setup (wave-uniform) ----
    const float4 roi = ((const float4*)rois)[bn];   // x1,y1,x2,y2
    const float x1 = roi.x, y1 = roi.y;
    const float w  = roi.z - roi.x;
    const float h  = roi.w - roi.y;

    float lvf = log2f(sqrtf(w * h) * (1.0f / 224.0f)) + 4.0f;
    int lv = (int)rintf(lvf);                   // RNE, matches jnp.round
    lv = min(max(lv, 2), 5) - 2;                // 0..3

    const float* fm = (lv == 0) ? fm2 : (lv == 1) ? fm3 : (lv == 2) ? fm4 : fm5;
    const int    H      = 256 >> lv;            // H == W
    const float  stride = (float)(4 << lv);
    const float  scale  = (float)(H - 1) / (stride * (float)H);

    // ---- sample coordinate for this cell ----
    const float gy = (float)jy * (1.0f / 6.0f);
    const float gx = (float)ix * (1.0f / 6.0f);
    const float cy = (y1 + gy * h) * scale;     // ref: ((y1+g*h)/stride/H)*(H-1)
    const float cx = (x1 + gx * w) * scale;

    const int vld = (cy >= 0.0f) & (cy <= (float)(H - 1)) &
                    (cx >= 0.0f) & (cx <= (float)(H - 1));

    const float cyc = fminf(fmaxf(cy, 0.0f), (float)(H - 1));
    const float cxc = fminf(fmaxf(cx, 0.0f), (float)(H - 1));
    const int   y0  = (int)floorf(cyc);
    const int   x0  = (int)floorf(cxc);
    const float yl  = cyc - (float)y0;
    const float xl  = cxc - (float)x0;
    const int   y1i = min(y0 + 1, H - 1);
    const int   x1i = min(x0 + 1, H - 1);

    // ---- gather + bilinear: lane handles 4 channels (float4) ----
    const int c = (threadIdx.x & 63) * 4;

    const float* base = fm + (size_t)b * (size_t)H * (size_t)H * CCH;
    const float* rowT = base + (size_t)y0  * H * CCH;
    const float* rowB = base + (size_t)y1i * H * CCH;

    const float4 tl = *(const float4*)(rowT + x0  * CCH + c);
    const float4 tr = *(const float4*)(rowT + x1i * CCH + c);
    const float4 bl = *(const float4*)(rowB + x0  * CCH + c);
    const float4 br = *(const float4*)(rowB + x1i * CCH + c);

    nfloat4 o;
    {
        const float tx = tl.x + (tr.x - tl.x) * xl;
        const float bx = bl.x + (br.x - bl.x) * xl;
        o.x = tx + (bx - tx) * yl;
    }
    {
        const float ty = tl.y + (tr.y - tl.y) * xl;
        const float by = bl.y + (br.y - bl.y) * xl;
        o.y = ty + (by - ty) * yl;
    }
    {
        const float tz = tl.z + (tr.z - tl.z) * xl;
        const float bz = bl.z + (br.z - bl.z) * xl;
        o.z = tz + (bz - tz) * yl;
    }
    {
        const float tw = tl.w + (tr.w - tl.w) * xl;
        const float bw = bl.w + (br.w - bl.w) * xl;
        o.w = tw + (bw - tw) * yl;
    }
    if (!vld) { o.x = 0.0f; o.y = 0.0f; o.z = 0.0f; o.w = 0.0f; }

    // write-once output: non-temporal to keep it out of L2
    nfloat4* dst = (nfloat4*)(out + (size_t)bn * NCELL * CCH + (size_t)cell * CCH + c);
    __builtin_nontemporal_store(o, dst);
}

extern "C" void kernel_launch(void* const* d_in, const int* in_sizes, int n_in,
                              void* d_out, int out_size, void* d_ws, size_t ws_size,
                              hipStream_t stream) {
    const float* fm2  = (const float*)d_in[0];
    const float* fm3  = (const float*)d_in[1];
    const float* fm4  = (const float*)d_in[2];
    const float* fm5  = (const float*)d_in[3];
    const float* rois = (const float*)d_in[4];
    float* out = (float*)d_out;

    dim3 grid((B_SZ * N_ROI * NCELL) / 4);   // 12544 blocks, 4 waves each
    dim3 block(256);
    hipLaunchKernelGGL(roialign_kernel, grid, block, 0, stream,
                       fm2, fm3, fm4, fm5, rois, out);
}

// Round 5
// 215.181 us; speedup vs baseline: 1.0523x; 1.0175x over previous
//
#include <hip/hip_runtime.h>

// ROIAlign (FPN multi-level, crop_and_resize style) for MI355X.
// Shapes (fixed): B=2, N=512, C=256, OUT=7, IMG=1024,
// strides {4,8,16,32} -> fm H=W {256,128,64,32}.
// Output read back by harness as float32 (reference f16 -> "else float*").
//
// R5 structure: block = 448 threads = 7 waves = one ROW of 7 cells for one
// ROI (row-mates share both bilinear y-rows -> L1 reuse). XCD swizzle:
// blockIdx = 8*(roi_hi*7 + row) + (roi&7), so all 7 blocks of one ROI land
// on the same XCD (xcd ~ blockIdx%8) -> ROI's ~200KB pixel set is filled
// into ONE per-XCD L2 instead of 8 (R4 scattered each ROI across all XCDs,
// ~8x L3->L2 fill traffic; theory: that was the ~70us limiter).

#define B_SZ   2
#define N_ROI  512
#define CCH    256
#define OUT_S  7
#define NCELL  (OUT_S * OUT_S)

typedef float nfloat4 __attribute__((ext_vector_type(4)));

__global__ __launch_bounds__(448)
void roialign_kernel(const float* __restrict__ fm2,
                     const float* __restrict__ fm3,
                     const float* __restrict__ fm4,
                     const float* __restrict__ fm5,
                     const float* __restrict__ rois,
                     float* __restrict__ out)
{
    // decode swizzled block id -> (roi, row); wave id -> column
    const int bidx = blockIdx.x;
    const int g    = bidx & 7;            // XCD slot == roi & 7
    const int q    = bidx >> 3;           // 0 .. 895
    const int ihi  = q / OUT_S;           // 0 .. 127  (roi >> 3)
    const int jy   = q - ihi * OUT_S;     // row 0..6
    const int bn   = (ihi << 3) | g;      // ROI id 0..1023
    const int ix   = threadIdx.x >> 6;    // column 0..6 (wave id in block)
    const int b    = bn >> 9;             // batch (N=512)

    // ---- per-ROI setup (wave-uniform) ----
    const float4 roi = ((const float4*)rois)[bn];   // x1,y1,x2,y2
    const float x1 = roi.x, y1 = roi.y;
    const float w  = roi.z - roi.x;
    const float h  = roi.w - roi.y;

    float lvf = log2f(sqrtf(w * h) * (1.0f / 224.0f)) + 4.0f;
    int lv = (int)rintf(lvf);                   // RNE, matches jnp.round
    lv = min(max(lv, 2), 5) - 2;                // 0..3

    const float* fm = (lv == 0) ? fm2 : (lv == 1) ? fm3 : (lv == 2) ? fm4 : fm5;
    const int    H      = 256 >> lv;            // H == W
    const float  stride = (float)(4 << lv);
    const float  scale  = (float)(H - 1) / (stride * (float)H);

    // ---- sample coordinate for this (row, col) cell ----
    const float gy = (float)jy * (1.0f / 6.0f);
    const float gx = (float)ix * (1.0f / 6.0f);
    const float cy = (y1 + gy * h) * scale;     // ref: ((y1+g*h)/stride/H)*(H-1)
    const float cx = (x1 + gx * w) * scale;

    const int vld = (cy >= 0.0f) & (cy <= (float)(H - 1)) &
                    (cx >= 0.0f) & (cx <= (float)(H - 1));

    const float cyc = fminf(fmaxf(cy, 0.0f), (float)(H - 1));
    const float cxc = fminf(fmaxf(cx, 0.0f), (float)(H - 1));
    const int   y0  = (int)floorf(cyc);
    const int   x0  = (int)floorf(cxc);
    const float yl  = cyc - (float)y0;
    const float xl  = cxc - (float)x0;
    const int   y1i = min(y0 + 1, H - 1);
    const int   x1i = min(x0 + 1, H - 1);

    // ---- gather + bilinear: lane handles 4 channels (float4) ----
    const int c = (threadIdx.x & 63) * 4;

    const float* base = fm + (size_t)b * (size_t)H * (size_t)H * CCH;
    const float* rowT = base + (size_t)y0  * H * CCH;
    const float* rowB = base + (size_t)y1i * H * CCH;

    const float4 tl = *(const float4*)(rowT + x0  * CCH + c);
    const float4 tr = *(const float4*)(rowT + x1i * CCH + c);
    const float4 bl = *(const float4*)(rowB + x0  * CCH + c);
    const float4 br = *(const float4*)(rowB + x1i * CCH + c);

    nfloat4 o;
    {
        const float tx = tl.x + (tr.x - tl.x) * xl;
        const float bx = bl.x + (br.x - bl.x) * xl;
        o.x = tx + (bx - tx) * yl;
    }
    {
        const float ty = tl.y + (tr.y - tl.y) * xl;
        const float by = bl.y + (br.y - bl.y) * xl;
        o.y = ty + (by - ty) * yl;
    }
    {
        const float tz = tl.z + (tr.z - tl.z) * xl;
        const float bz = bl.z + (br.z - bl.z) * xl;
        o.z = tz + (bz - tz) * yl;
    }
    {
        const float tw = tl.w + (tr.w - tl.w) * xl;
        const float bw = bl.w + (br.w - bl.w) * xl;
        o.w = tw + (bw - tw) * yl;
    }
    if (!vld) { o.x = 0.0f; o.y = 0.0f; o.z = 0.0f; o.w = 0.0f; }

    // write-once output: non-temporal to keep it out of L2
    const int cell = jy * OUT_S + ix;
    nfloat4* dst = (nfloat4*)(out + (size_t)bn * NCELL * CCH + (size_t)cell * CCH + c);
    __builtin_nontemporal_store(o, dst);
}

extern "C" void kernel_launch(void* const* d_in, const int* in_sizes, int n_in,
                              void* d_out, int out_size, void* d_ws, size_t ws_size,
                              hipStream_t stream) {
    const float* fm2  = (const float*)d_in[0];
    const float* fm3  = (const float*)d_in[1];
    const float* fm4  = (const float*)d_in[2];
    const float* fm5  = (const float*)d_in[3];
    const float* rois = (const float*)d_in[4];
    float* out = (float*)d_out;

    dim3 grid(8 * (N_ROI * B_SZ / 8) * OUT_S);   // 7168 blocks (XCD-swizzled)
    dim3 block(64 * OUT_S);                      // 448 threads = 7 waves = 1 row
    hipLaunchKernelGGL(roialign_kernel, grid, block, 0, stream,
                       fm2, fm3, fm4, fm5, rois, out);
}